// Round 2
// baseline (191.665 us; speedup 1.0000x reference)
//
#include <hip/hip_runtime.h>

#define N_ROWS 8192
#define DIM    512

typedef __attribute__((ext_vector_type(4))) float frag_cd;      // 4 fp32 acc
typedef __attribute__((ext_vector_type(4))) int   v4i;          // 16B
typedef __attribute__((ext_vector_type(8))) int   v8i;          // 32B MX A/B fragment

// fp32 -> OCP e4m3fn, RNE, FTZ below 2^-6 (negligible for N(0,1) data).
__device__ __forceinline__ unsigned f2fp8(float x) {
    float a = fabsf(x);
    unsigned s = (__float_as_uint(x) >> 31) << 7;
    if (a < 0.015625f) return s;                 // FTZ subnormals
    a = fminf(a, 448.f);                         // e4m3fn max
    unsigned u = __float_as_uint(a);
    u += 0x7FFFFu + ((u >> 20) & 1u);            // RNE round mantissa to 3 bits
    unsigned exp = (u >> 23) - 120u;             // fp32exp-127+7 in [1,15]
    unsigned mant = (u >> 20) & 7u;
    return s | (exp << 3) | mant;
}
__device__ __forceinline__ unsigned pack4fp8(float4 v) {
    return f2fp8(v.x) | (f2fp8(v.y) << 8) | (f2fp8(v.z) << 16) | (f2fp8(v.w) << 24);
}
// order-preserving f32 -> u32 key (monotone), so atomicMax(uint) == float max
__device__ __forceinline__ unsigned enc_f32(float f) {
    unsigned u = __float_as_uint(f);
    return (u & 0x80000000u) ? ~u : (u | 0x80000000u);
}
__device__ __forceinline__ float dec_f32(unsigned k) {
    return __uint_as_float((k & 0x80000000u) ? (k & 0x7FFFFFFFu) : ~k);
}

// ---- TILED fp8 layout for mfma_scale 16x16x128 (K-step = 128) ----
// Chunk (cr, kp2) = 16 rows x 128 K-cols = 2 KB at byte cr*8192 + kp2*2048.
// Within chunk: half h (bytes 16h..16h+15 of each lane's 32B fragment) at
//   h*1024 + (q*16 + rin)*16,  q = K-block (l>>4 of consumer), rin = row&15.
// Covers row rin, K = kp2*128 + q*32 + h*16 + [0..15].
// Consumer lane l reads unit (q*16+l15) = l -> offset lane*16: fully
// contiguous ds_read_b128 across the wave (0 bank conflicts, as measured).

// ---- kernel 1: convert + diag + init (now 2048 blocks, 1 row/wave) ----
__global__ __launch_bounds__(256) void k_prep(const float* __restrict__ imgs,
                                              const float* __restrict__ caps,
                                              unsigned char* __restrict__ fimgs,
                                              unsigned char* __restrict__ fcaps,
                                              float* __restrict__ diag,
                                              unsigned* __restrict__ rowmax,
                                              unsigned* __restrict__ colmax,
                                              float* __restrict__ out) {
    const int b  = blockIdx.x;            // 0..2047
    const int cr = b >> 2;                // row-chunk 0..511
    const int t  = threadIdx.x;
    const int w = t >> 6, l = t & 63;
    const int row = ((b & 3) << 2) + w;   // 0..15 within chunk
    if (b == 0 && t == 0) out[0] = 0.f;   // zero accumulator for k_final
    const int r = cr * 16 + row;
    const float* ar = imgs + (size_t)r * DIM + l * 8;
    const float* br = caps + (size_t)r * DIM + l * 8;
    float4 a0 = *(const float4*)ar, a1 = *(const float4*)(ar + 4);
    float4 b0 = *(const float4*)br, b1 = *(const float4*)(br + 4);
    uint2 oa, ob;
    oa.x = pack4fp8(a0); oa.y = pack4fp8(a1);
    ob.x = pack4fp8(b0); ob.y = pack4fp8(b1);
    // lane l holds K-cols 8l..8l+7: kp2=l>>4, q=(l>>2)&3, h=(l>>1)&1, pos=8*(l&1)
    const size_t addr = (size_t)cr * 8192 + (size_t)((l >> 4) << 11)
                      + (((l >> 1) & 1) << 10)
                      + ((((l >> 2) & 3) << 4) + row) * 16 + ((l & 1) << 3);
    *(uint2*)(fimgs + addr) = oa;
    *(uint2*)(fcaps + addr) = ob;
    float s = a0.x * b0.x + a0.y * b0.y + a0.z * b0.z + a0.w * b0.w
            + a1.x * b1.x + a1.y * b1.y + a1.z * b1.z + a1.w * b1.w;
    #pragma unroll
    for (int m = 1; m < 64; m <<= 1) s += __shfl_xor(s, m, 64);
    if (l == 0) { diag[r] = s; rowmax[r] = 0u; colmax[r] = 0u; }
}

// ---- kernel 2: fused MX-fp8 NT-GEMM (K=128/instr, scale=1.0) ----
// Same 64x128 tile, same XCD-aware job swizzle, same verified epilogue.
// LDS 48 KB -> 3 blocks/CU.
__global__ __launch_bounds__(256, 3) void k_gemm(const unsigned char* __restrict__ A,
                                                 const unsigned char* __restrict__ B,
                                                 unsigned* __restrict__ rowmax,
                                                 unsigned* __restrict__ colmax) {
    __shared__ unsigned char sA[2][8192];    // 4 chunk slots x 2 KB
    __shared__ unsigned char sB[2][16384];   // 8 chunk slots x 2 KB
    const int tid = threadIdx.x;
    const int w = tid >> 6, lane = tid & 63;
    // XCD-aware swizzle of the flat job id
    const int f = (int)blockIdx.x;
    const int jb = (f & 7) * 8 + ((f >> 3) & 7);   // 0..63
    const int ib = f >> 6;                          // 0..127
    const int j0 = jb << 7, i0 = ib << 6;
    const int q = lane >> 4, l15 = lane & 15;
    const int wr = (w & 1) << 5, wc = (w >> 1) << 6;   // wave tile origin

    const unsigned char* Ab = A + (size_t)(i0 >> 4) * 8192 + lane * 16;
    const unsigned char* Bb = B + (size_t)(j0 >> 4) * 8192 + lane * 16;

    frag_cd acc[2][4] = {};

    auto stage = [&](int bi, int kp2) {
        // wave w: A chunk w (2 loads), B chunks 2w,2w+1 (4 loads) = 6 loads
        #pragma unroll
        for (int j = 0; j < 2; ++j)
            __builtin_amdgcn_global_load_lds(
                (const __attribute__((address_space(1))) unsigned int*)(Ab + (size_t)w * 8192 + kp2 * 2048 + j * 1024),
                (__attribute__((address_space(3))) unsigned int*)(&sA[bi][(w << 11) + (j << 10) + (lane << 4)]), 16, 0, 0);
        #pragma unroll
        for (int s = 0; s < 2; ++s) {
            const int ch = 2 * w + s;
            #pragma unroll
            for (int j = 0; j < 2; ++j)
                __builtin_amdgcn_global_load_lds(
                    (const __attribute__((address_space(1))) unsigned int*)(Bb + (size_t)ch * 8192 + kp2 * 2048 + j * 1024),
                    (__attribute__((address_space(3))) unsigned int*)(&sB[bi][(ch << 11) + (j << 10) + (lane << 4)]), 16, 0, 0);
        }
    };

    stage(0, 0);
    __syncthreads();   // cold drain (once)

    const int u16 = lane << 4;   // contiguous per-lane 16B unit

    #pragma unroll
    for (int kp2 = 0; kp2 < 4; ++kp2) {
        const int cur = kp2 & 1, nxt = cur ^ 1;
        if (kp2 < 3) stage(nxt, kp2 + 1);   // in flight during compute below

        v8i af[2], bf[4];
        #pragma unroll
        for (int r = 0; r < 2; ++r) {         // A chunk = (w&1)*2 + r
            const int ch = ((w & 1) << 1) + r;
            v4i lo = *(const v4i*)(&sA[cur][(ch << 11) + u16]);
            v4i hi = *(const v4i*)(&sA[cur][(ch << 11) + 1024 + u16]);
            v8i v;
            v[0] = lo[0]; v[1] = lo[1]; v[2] = lo[2]; v[3] = lo[3];
            v[4] = hi[0]; v[5] = hi[1]; v[6] = hi[2]; v[7] = hi[3];
            af[r] = v;
        }
        #pragma unroll
        for (int c = 0; c < 4; ++c) {         // B chunk = (w>>1)*4 + c
            const int ch = ((w >> 1) << 2) + c;
            v4i lo = *(const v4i*)(&sB[cur][(ch << 11) + u16]);
            v4i hi = *(const v4i*)(&sB[cur][(ch << 11) + 1024 + u16]);
            v8i v;
            v[0] = lo[0]; v[1] = lo[1]; v[2] = lo[2]; v[3] = lo[3];
            v[4] = hi[0]; v[5] = hi[1]; v[6] = hi[2]; v[7] = hi[3];
            bf[c] = v;
        }
        #pragma unroll
        for (int r = 0; r < 2; ++r)
            #pragma unroll
            for (int c = 0; c < 4; ++c)
                // fp8(e4m3) x fp8, per-block e8m0 scales all = 127 (=2^0 exact)
                acc[r][c] = __builtin_amdgcn_mfma_scale_f32_16x16x128_f8f6f4(
                    af[r], bf[c], acc[r][c], 0, 0,
                    0, 0x7F7F7F7F, 0, 0x7F7F7F7F);

        __syncthreads();
    }

    // ---- epilogue: diagonal flip + row/col max + device atomics ----
    // C/D layout: col = lane&15, row = (lane>>4)*4 + reg (dtype-independent)
    const bool dblk = ((i0 >> 7) == jb);
    #pragma unroll
    for (int r = 0; r < 2; ++r)
        #pragma unroll
        for (int c = 0; c < 4; ++c)
            #pragma unroll
            for (int g = 0; g < 4; ++g) {
                float fv = acc[r][c][g];
                const int gi = wr + (r << 4) + (q << 2) + g;          // row in block
                const int gj = wc + (c << 4) + l15;                   // col in block
                if (dblk && (i0 + gi) == (j0 + gj)) fv = -fv;         // s[i][i] = -diag
                acc[r][c][g] = fv;
            }

    #pragma unroll
    for (int r = 0; r < 2; ++r)
        #pragma unroll
        for (int g = 0; g < 4; ++g) {
            float m = fmaxf(fmaxf(acc[r][0][g], acc[r][1][g]),
                            fmaxf(acc[r][2][g], acc[r][3][g]));
            m = fmaxf(m, __shfl_xor(m, 1, 64));
            m = fmaxf(m, __shfl_xor(m, 2, 64));
            m = fmaxf(m, __shfl_xor(m, 4, 64));
            m = fmaxf(m, __shfl_xor(m, 8, 64));
            if (l15 == 0)
                atomicMax(&rowmax[i0 + wr + (r << 4) + (q << 2) + g], enc_f32(m));
        }
    #pragma unroll
    for (int c = 0; c < 4; ++c) {
        float m = acc[0][c][0];
        #pragma unroll
        for (int r = 0; r < 2; ++r)
            #pragma unroll
            for (int g = 0; g < 4; ++g) m = fmaxf(m, acc[r][c][g]);
        m = fmaxf(m, __shfl_xor(m, 16, 64));
        m = fmaxf(m, __shfl_xor(m, 32, 64));
        if (q == 0)
            atomicMax(&colmax[j0 + wc + (c << 4) + l15], enc_f32(m));
    }
}

// ---- kernel 3: hinge terms, 32 blocks + one atomicAdd per block ----
__global__ __launch_bounds__(256) void k_final(const unsigned* __restrict__ rowmax,
                                               const unsigned* __restrict__ colmax,
                                               const float* __restrict__ diag,
                                               float* __restrict__ out) {
    const int idx = blockIdx.x * 256 + threadIdx.x;
    const float d = diag[idx];
    float s = fmaxf(dec_f32(rowmax[idx]) + 0.2f - d, 0.f)    // neg_img
            + fmaxf(dec_f32(colmax[idx]) + 0.2f - d, 0.f);   // neg_cap
    #pragma unroll
    for (int m = 1; m < 64; m <<= 1) s += __shfl_xor(s, m, 64);
    __shared__ float red[4];
    if ((threadIdx.x & 63) == 0) red[threadIdx.x >> 6] = s;
    __syncthreads();
    if (threadIdx.x == 0)
        atomicAdd(out, red[0] + red[1] + red[2] + red[3]);
}

extern "C" void kernel_launch(void* const* d_in, const int* in_sizes, int n_in,
                              void* d_out, int out_size, void* d_ws, size_t ws_size,
                              hipStream_t stream) {
    const float* imgs = (const float*)d_in[0];
    const float* caps = (const float*)d_in[1];
    float* out = (float*)d_out;

    char* ws = (char*)d_ws;
    unsigned char* fimgs = (unsigned char*)ws;                         // 4 MB tiled fp8
    unsigned char* fcaps = (unsigned char*)(ws + 4194304);             // 4 MB tiled fp8
    float*    diag   = (float*)   (ws + 8388608);                      // 32 KB
    unsigned* rowmax = (unsigned*)(ws + 8388608 + 32768);              // 32 KB
    unsigned* colmax = (unsigned*)(ws + 8388608 + 65536);              // 32 KB

    k_prep<<<2048, 256, 0, stream>>>(imgs, caps, fimgs, fcaps,
                                     diag, rowmax, colmax, out);
    k_gemm<<<8192, 256, 0, stream>>>(fimgs, fcaps, rowmax, colmax);
    k_final<<<N_ROWS / 256, 256, 0, stream>>>(rowmax, colmax, diag, out);
}

// Round 3
// 175.943 us; speedup vs baseline: 1.0894x; 1.0894x over previous
//
#include <hip/hip_runtime.h>

#define N_ROWS 8192
#define DIM    512

typedef __attribute__((ext_vector_type(4))) float frag_cd;      // 4 fp32 acc
typedef __attribute__((ext_vector_type(4))) int   v4i;          // 16B
typedef __attribute__((ext_vector_type(8))) int   v8i;          // 32B MX A/B fragment

// fp32 -> OCP e4m3fn, RNE, FTZ below 2^-6 (negligible for N(0,1) data).
__device__ __forceinline__ unsigned f2fp8(float x) {
    float a = fabsf(x);
    unsigned s = (__float_as_uint(x) >> 31) << 7;
    if (a < 0.015625f) return s;                 // FTZ subnormals
    a = fminf(a, 448.f);                         // e4m3fn max
    unsigned u = __float_as_uint(a);
    u += 0x7FFFFu + ((u >> 20) & 1u);            // RNE round mantissa to 3 bits
    unsigned exp = (u >> 23) - 120u;             // fp32exp-127+7 in [1,15]
    unsigned mant = (u >> 20) & 7u;
    return s | (exp << 3) | mant;
}
__device__ __forceinline__ unsigned pack4fp8(float4 v) {
    return f2fp8(v.x) | (f2fp8(v.y) << 8) | (f2fp8(v.z) << 16) | (f2fp8(v.w) << 24);
}
// order-preserving f32 -> u32 key (monotone), so atomicMax(uint) == float max
__device__ __forceinline__ unsigned enc_f32(float f) {
    unsigned u = __float_as_uint(f);
    return (u & 0x80000000u) ? ~u : (u | 0x80000000u);
}
__device__ __forceinline__ float dec_f32(unsigned k) {
    return __uint_as_float((k & 0x80000000u) ? (k & 0x7FFFFFFFu) : ~k);
}

// ---- TILED fp8 layout for mfma_scale 16x16x128 (round-2 verified exact) ----
// Chunk (cr, kp2) = 16 rows x 128 K-cols = 2 KB at byte cr*8192 + kp2*2048.
// Lane l's 32B fragment: lo 16B at chunk + lane*16, hi 16B at +1024.
// Fully contiguous 1KB per wave per load instruction.

// ---- kernel 1: convert + diag + init (round-2 verbatim, verified) ----
__global__ __launch_bounds__(256) void k_prep(const float* __restrict__ imgs,
                                              const float* __restrict__ caps,
                                              unsigned char* __restrict__ fimgs,
                                              unsigned char* __restrict__ fcaps,
                                              float* __restrict__ diag,
                                              unsigned* __restrict__ rowmax,
                                              unsigned* __restrict__ colmax,
                                              float* __restrict__ out) {
    const int b  = blockIdx.x;            // 0..2047
    const int cr = b >> 2;                // row-chunk 0..511
    const int t  = threadIdx.x;
    const int w = t >> 6, l = t & 63;
    const int row = ((b & 3) << 2) + w;   // 0..15 within chunk
    if (b == 0 && t == 0) out[0] = 0.f;   // zero accumulator for k_final
    const int r = cr * 16 + row;
    const float* ar = imgs + (size_t)r * DIM + l * 8;
    const float* br = caps + (size_t)r * DIM + l * 8;
    float4 a0 = *(const float4*)ar, a1 = *(const float4*)(ar + 4);
    float4 b0 = *(const float4*)br, b1 = *(const float4*)(br + 4);
    uint2 oa, ob;
    oa.x = pack4fp8(a0); oa.y = pack4fp8(a1);
    ob.x = pack4fp8(b0); ob.y = pack4fp8(b1);
    // lane l holds K-cols 8l..8l+7: kp2=l>>4, q=(l>>2)&3, h=(l>>1)&1, pos=8*(l&1)
    const size_t addr = (size_t)cr * 8192 + (size_t)((l >> 4) << 11)
                      + (((l >> 1) & 1) << 10)
                      + ((((l >> 2) & 3) << 4) + row) * 16 + ((l & 1) << 3);
    *(uint2*)(fimgs + addr) = oa;
    *(uint2*)(fcaps + addr) = ob;
    float s = a0.x * b0.x + a0.y * b0.y + a0.z * b0.z + a0.w * b0.w
            + a1.x * b1.x + a1.y * b1.y + a1.z * b1.z + a1.w * b1.w;
    #pragma unroll
    for (int m = 1; m < 64; m <<= 1) s += __shfl_xor(s, m, 64);
    if (l == 0) { diag[r] = s; rowmax[r] = 0u; colmax[r] = 0u; }
}

// ---- kernel 2: barrier-free direct-to-register MX-fp8 NT-GEMM ----
// No LDS, no __syncthreads: each wave owns a 64x64 output tile and loads
// its fragments straight from L2 (operands are L2-resident; B panel per
// XCD = 512 KB). Compiler is free to pipeline loads across K with counted
// waitcnts -- no barrier ever forces a vmcnt(0) drain (the round-1/2
// structural stall). Block = 4 waves covering 128x128 so each fragment is
// requested by exactly 2 waves (L1 dedup). Epilogue verified in round 2.
__global__ __launch_bounds__(256, 2) void k_gemm(const unsigned char* __restrict__ A,
                                                 const unsigned char* __restrict__ B,
                                                 unsigned* __restrict__ rowmax,
                                                 unsigned* __restrict__ colmax) {
    const int tid = threadIdx.x;
    const int w = tid >> 6, lane = tid & 63;
    // XCD-aware swizzle: xcd = f&7 owns jb in {8x..8x+7} (512 KB B-panel);
    // 8 consecutive same-xcd jobs share one A-panel (64 KB). Heuristic only.
    const int f = (int)blockIdx.x;                 // 0..4095
    const int jb = (f & 7) * 8 + ((f >> 3) & 7);   // 0..63 (128-col panel)
    const int ib = f >> 6;                          // 0..63 (128-row panel)
    const int j0 = jb << 7, i0 = ib << 7;
    const int q = lane >> 4, l15 = lane & 15;
    const int wr = (w & 1) << 6, wc = (w >> 1) << 6;   // wave tile origin in block

    const unsigned char* Ab = A + (size_t)((i0 >> 4) + ((w & 1) << 2)) * 8192 + lane * 16;
    const unsigned char* Bb = B + (size_t)((j0 >> 4) + ((w >> 1) << 2)) * 8192 + lane * 16;

    frag_cd acc[4][4] = {};

    union U { v8i v; struct { v4i lo, hi; } s; };

    #pragma unroll
    for (int kp2 = 0; kp2 < 4; ++kp2) {
        U af[4], bf[4];
        #pragma unroll
        for (int r = 0; r < 4; ++r) {
            af[r].s.lo = *(const v4i*)(Ab + (size_t)r * 8192 + kp2 * 2048);
            af[r].s.hi = *(const v4i*)(Ab + (size_t)r * 8192 + kp2 * 2048 + 1024);
        }
        #pragma unroll
        for (int c = 0; c < 4; ++c) {
            bf[c].s.lo = *(const v4i*)(Bb + (size_t)c * 8192 + kp2 * 2048);
            bf[c].s.hi = *(const v4i*)(Bb + (size_t)c * 8192 + kp2 * 2048 + 1024);
        }
        #pragma unroll
        for (int r = 0; r < 4; ++r)
            #pragma unroll
            for (int c = 0; c < 4; ++c)
                // fp8(e4m3) x fp8, per-block e8m0 scales all = 127 (=2^0 exact)
                acc[r][c] = __builtin_amdgcn_mfma_scale_f32_16x16x128_f8f6f4(
                    af[r].v, bf[c].v, acc[r][c], 0, 0,
                    0, 0x7F7F7F7F, 0, 0x7F7F7F7F);
    }

    // ---- epilogue: diagonal flip + row/col max + device atomics ----
    // C/D layout (16x16 family): col = lane&15, row = (lane>>4)*4 + reg
    const bool dblk = (i0 == j0);
    #pragma unroll
    for (int r = 0; r < 4; ++r)
        #pragma unroll
        for (int c = 0; c < 4; ++c)
            #pragma unroll
            for (int g = 0; g < 4; ++g) {
                float fv = acc[r][c][g];
                const int gi = wr + (r << 4) + (q << 2) + g;          // row in block
                const int gj = wc + (c << 4) + l15;                   // col in block
                if (dblk && (i0 + gi) == (j0 + gj)) fv = -fv;         // s[i][i] = -diag
                acc[r][c][g] = fv;
            }

    #pragma unroll
    for (int r = 0; r < 4; ++r)
        #pragma unroll
        for (int g = 0; g < 4; ++g) {
            float m = fmaxf(fmaxf(acc[r][0][g], acc[r][1][g]),
                            fmaxf(acc[r][2][g], acc[r][3][g]));
            m = fmaxf(m, __shfl_xor(m, 1, 64));
            m = fmaxf(m, __shfl_xor(m, 2, 64));
            m = fmaxf(m, __shfl_xor(m, 4, 64));
            m = fmaxf(m, __shfl_xor(m, 8, 64));
            if (l15 == 0)
                atomicMax(&rowmax[i0 + wr + (r << 4) + (q << 2) + g], enc_f32(m));
        }
    #pragma unroll
    for (int c = 0; c < 4; ++c) {
        float m = acc[0][c][0];
        #pragma unroll
        for (int r = 0; r < 4; ++r)
            #pragma unroll
            for (int g = 0; g < 4; ++g) m = fmaxf(m, acc[r][c][g]);
        m = fmaxf(m, __shfl_xor(m, 16, 64));
        m = fmaxf(m, __shfl_xor(m, 32, 64));
        if (q == 0)
            atomicMax(&colmax[j0 + wc + (c << 4) + l15], enc_f32(m));
    }
}

// ---- kernel 3: hinge terms, 32 blocks + one atomicAdd per block ----
__global__ __launch_bounds__(256) void k_final(const unsigned* __restrict__ rowmax,
                                               const unsigned* __restrict__ colmax,
                                               const float* __restrict__ diag,
                                               float* __restrict__ out) {
    const int idx = blockIdx.x * 256 + threadIdx.x;
    const float d = diag[idx];
    float s = fmaxf(dec_f32(rowmax[idx]) + 0.2f - d, 0.f)    // neg_img
            + fmaxf(dec_f32(colmax[idx]) + 0.2f - d, 0.f);   // neg_cap
    #pragma unroll
    for (int m = 1; m < 64; m <<= 1) s += __shfl_xor(s, m, 64);
    __shared__ float red[4];
    if ((threadIdx.x & 63) == 0) red[threadIdx.x >> 6] = s;
    __syncthreads();
    if (threadIdx.x == 0)
        atomicAdd(out, red[0] + red[1] + red[2] + red[3]);
}

extern "C" void kernel_launch(void* const* d_in, const int* in_sizes, int n_in,
                              void* d_out, int out_size, void* d_ws, size_t ws_size,
                              hipStream_t stream) {
    const float* imgs = (const float*)d_in[0];
    const float* caps = (const float*)d_in[1];
    float* out = (float*)d_out;

    char* ws = (char*)d_ws;
    unsigned char* fimgs = (unsigned char*)ws;                         // 4 MB tiled fp8
    unsigned char* fcaps = (unsigned char*)(ws + 4194304);             // 4 MB tiled fp8
    float*    diag   = (float*)   (ws + 8388608);                      // 32 KB
    unsigned* rowmax = (unsigned*)(ws + 8388608 + 32768);              // 32 KB
    unsigned* colmax = (unsigned*)(ws + 8388608 + 65536);              // 32 KB

    k_prep<<<2048, 256, 0, stream>>>(imgs, caps, fimgs, fcaps,
                                     diag, rowmax, colmax, out);
    k_gemm<<<4096, 256, 0, stream>>>(fimgs, fcaps, rowmax, colmax);
    k_final<<<N_ROWS / 256, 256, 0, stream>>>(rowmax, colmax, diag, out);
}